// Round 4
// baseline (173.322 us; speedup 1.0000x reference)
//
#include <hip/hip_runtime.h>
#include <hip/hip_cooperative_groups.h>

namespace cg = cooperative_groups;

#define BATCH 4
#define NROWS 2048
#define IN_DIM 1024
#define OUT_DIM 512
#define NBLK 256
#define RPB 32                    // rows per block

// ---------------- shared phase implementations ----------------

// P1: w2[col] = sum_d fc_w[d][col] * a2[d]   (bid 0..15, 64 cols each)
__device__ __forceinline__ void ph_w2(int bid, int t,
                                      const float* __restrict__ fc_w,
                                      const float* __restrict__ attn_w,
                                      float* __restrict__ w2,
                                      float* red) {
    int w = t >> 6, lane = t & 63;
    int col = (bid << 6) + lane;
    const float* fw = fc_w + col;
    int d0 = w << 7;
    float acc = 0.f;
#pragma unroll 4
    for (int d = 0; d < 128; ++d)
        acc += fw[(size_t)(d0 + d) * IN_DIM] * attn_w[OUT_DIM + d0 + d];
    red[t] = acc;
    __syncthreads();
    if (t < 64)
        w2[(bid << 6) + t] = (red[t] + red[64 + t]) + (red[128 + t] + red[192 + t]);
    __syncthreads();
}

// P2: s2[row] = dot(x[row], w2) for rows bid*32 .. +31 (wave handles 8 rows)
__device__ __forceinline__ void ph_s2(int bid, int t,
                                      const float* __restrict__ x,
                                      const float* __restrict__ w2,
                                      float* __restrict__ s2,
                                      float* sbuf) {
    int w = t >> 6, lane = t & 63;
    ((float4*)sbuf)[t] = ((const float4*)w2)[t];    // 1024 floats
    __syncthreads();
    const float4* w2s = (const float4*)sbuf;
    size_t row0 = (size_t)bid * RPB;
#pragma unroll
    for (int rr = 0; rr < 8; ++rr) {
        size_t row = row0 + (w << 3) + rr;
        const float4* xr = (const float4*)(x + row * IN_DIM);
        float acc = 0.f;
#pragma unroll
        for (int k = 0; k < 4; ++k) {
            float4 a = xr[lane + (k << 6)], u = w2s[lane + (k << 6)];
            acc += a.x * u.x + a.y * u.y + a.z * u.z + a.w * u.w;
        }
        for (int off = 32; off; off >>= 1) acc += __shfl_down(acc, off, 64);
        if (lane == 0) s2[row] = acc;
    }
    __syncthreads();
}

// P3: batch softmax stats (redundant per block) + weighted partial of own rows
__device__ __forceinline__ void ph_part(int bid, int t,
                                        const float* __restrict__ x,
                                        const float* __restrict__ s2,
                                        float* __restrict__ part,
                                        float* red, float* wgt) {
    int b = bid >> 6;                         // 64 blocks per batch
    const float* s2b = s2 + ((size_t)b << 11);
    float lv[8], lm = -1e30f;
#pragma unroll
    for (int j = 0; j < 8; ++j) { lv[j] = s2b[t + (j << 8)]; lm = fmaxf(lm, lv[j]); }
    red[t] = lm; __syncthreads();
    for (int o = 128; o; o >>= 1) { if (t < o) red[t] = fmaxf(red[t], red[t + o]); __syncthreads(); }
    float M = red[0]; __syncthreads();
    float ls = 0.f;
#pragma unroll
    for (int j = 0; j < 8; ++j) ls += __expf(lv[j] - M);
    red[t] = ls; __syncthreads();
    for (int o = 128; o; o >>= 1) { if (t < o) red[t] += red[t + o]; __syncthreads(); }
    float invZ = 1.f / red[0];

    int nloc = (bid & 63) * RPB;
    if (t < RPB) wgt[t] = __expf(s2b[nloc + t] - M) * invZ;
    __syncthreads();

    size_t row0 = (size_t)bid * RPB;
    const float4* xb = (const float4*)(x + row0 * IN_DIM);
    float4 acc = {0.f, 0.f, 0.f, 0.f};
#pragma unroll 8
    for (int r = 0; r < RPB; ++r) {
        float wr = wgt[r];
        float4 v = xb[(r << 8) + t];
        acc.x += wr * v.x; acc.y += wr * v.y; acc.z += wr * v.z; acc.w += wr * v.w;
    }
    ((float4*)(part + ((size_t)bid << 10)))[t] = acc;
    __syncthreads();
}

// P4: y[b][i] = sum over the batch's 64 chunk partials (bid 0..63)
__device__ __forceinline__ void ph_yred(int bid, int t,
                                        const float* __restrict__ part,
                                        float* __restrict__ y,
                                        float* red) {
    int w = t >> 6, lane = t & 63;
    int b2 = bid >> 4, isl = bid & 15;
    int col = (isl << 6) + lane;
    const float* pb = part + ((size_t)b2) * 64 * IN_DIM;
    float acc = 0.f;
#pragma unroll 4
    for (int c = (w << 4); c < (w << 4) + 16; ++c)
        acc += pb[((size_t)c << 10) + col];
    red[t] = acc; __syncthreads();
    if (t < 64)
        y[(b2 << 10) + (isl << 6) + t] =
            (red[t] + red[64 + t]) + (red[128 + t] + red[192 + t]);
    __syncthreads();
}

// P5: c[b][d] = dot(y[b], fc_w[d]) + fc_b[d]  (bid 0..127, 16 d each)
__device__ __forceinline__ void ph_c(int bid, int t,
                                     const float* __restrict__ y,
                                     const float* __restrict__ fc_w,
                                     const float* __restrict__ fc_b,
                                     float* __restrict__ cb,
                                     float* sbuf) {
    int w = t >> 6, lane = t & 63;
    int bb = bid >> 5, dsl = bid & 31;
    ((float4*)sbuf)[t] = ((const float4*)(y + ((size_t)bb << 10)))[t];
    __syncthreads();
    const float4* ys = (const float4*)sbuf;
#pragma unroll
    for (int q = 0; q < 4; ++q) {
        int d = (dsl << 4) + (w << 2) + q;
        const float4* fr = (const float4*)(fc_w + ((size_t)d << 10));
        float acc = 0.f;
#pragma unroll
        for (int k = 0; k < 4; ++k) {
            float4 a = fr[lane + (k << 6)], u = ys[lane + (k << 6)];
            acc += a.x * u.x + a.y * u.y + a.z * u.z + a.w * u.w;
        }
        for (int off = 32; off; off >>= 1) acc += __shfl_down(acc, off, 64);
        if (lane == 0) cb[(bb << 9) + d] = acc + fc_b[d];
    }
    __syncthreads();
}

// P6: out rows bid*32 .. +31 = c[b,:]
__device__ __forceinline__ void ph_bcast(int bid, int t,
                                         const float* __restrict__ cb,
                                         float* __restrict__ out,
                                         float* sbuf) {
    int b = bid >> 6;
    if (t < 128) ((float4*)sbuf)[t] = ((const float4*)(cb + ((size_t)b << 9)))[t];
    __syncthreads();
    float4* o4 = (float4*)out + ((size_t)bid << 12);   // 32 rows * 128 f4
#pragma unroll
    for (int j = 0; j < 16; ++j) {
        int idx = t + (j << 8);
        o4[idx] = ((float4*)sbuf)[idx & 127];
    }
    __syncthreads();
}

// ---------------- cooperative single-dispatch kernel ----------------
__global__ void __launch_bounds__(256)
coop_all(const float* __restrict__ x,
         const float* __restrict__ fc_w,
         const float* __restrict__ fc_b,
         const float* __restrict__ attn_w,
         float* __restrict__ ws,
         float* __restrict__ out)
{
    float* w2   = ws;                          // 1024
    float* s2   = ws + 1024;                   // 8192
    float* part = s2 + BATCH * NROWS;          // 256*1024 = 262144
    float* y    = part + (size_t)NBLK * IN_DIM;// 4096
    float* cb   = y + BATCH * IN_DIM;          // 2048
    // total 277,504 floats = 1.11 MB (same footprint R1 proved fits ws)

    cg::grid_group grid = cg::this_grid();
    const int bid = blockIdx.x, t = threadIdx.x;

    __shared__ float sbuf[1024];
    __shared__ float red[256];
    __shared__ float wgt[RPB];

    if (bid < 16) ph_w2(bid, t, fc_w, attn_w, w2, red);
    grid.sync();
    ph_s2(bid, t, x, w2, s2, sbuf);
    grid.sync();
    ph_part(bid, t, x, s2, part, red, wgt);
    grid.sync();
    if (bid < 64) ph_yred(bid, t, part, y, red);
    grid.sync();
    if (bid < 128) ph_c(bid, t, y, fc_w, fc_b, cb, sbuf);
    grid.sync();
    ph_bcast(bid, t, cb, out, sbuf);
}

// ---------------- fallback: same phases as separate kernels ----------------
__global__ void __launch_bounds__(256) fb_w2(const float* fc_w, const float* attn_w, float* w2) {
    __shared__ float red[256];
    ph_w2(blockIdx.x, threadIdx.x, fc_w, attn_w, w2, red);
}
__global__ void __launch_bounds__(256) fb_s2(const float* x, const float* w2, float* s2) {
    __shared__ float sbuf[1024];
    ph_s2(blockIdx.x, threadIdx.x, x, w2, s2, sbuf);
}
__global__ void __launch_bounds__(256) fb_part(const float* x, const float* s2, float* part) {
    __shared__ float red[256];
    __shared__ float wgt[RPB];
    ph_part(blockIdx.x, threadIdx.x, x, s2, part, red, wgt);
}
__global__ void __launch_bounds__(256) fb_yred(const float* part, float* y) {
    __shared__ float red[256];
    ph_yred(blockIdx.x, threadIdx.x, part, y, red);
}
__global__ void __launch_bounds__(256) fb_c(const float* y, const float* fc_w, const float* fc_b, float* cb) {
    __shared__ float sbuf[1024];
    ph_c(blockIdx.x, threadIdx.x, y, fc_w, fc_b, cb, sbuf);
}
__global__ void __launch_bounds__(256) fb_bcast(const float* cb, float* out) {
    __shared__ float sbuf[1024];
    ph_bcast(blockIdx.x, threadIdx.x, cb, out, sbuf);
}

extern "C" void kernel_launch(void* const* d_in, const int* in_sizes, int n_in,
                              void* d_out, int out_size, void* d_ws, size_t ws_size,
                              hipStream_t stream) {
    const float* x      = (const float*)d_in[0];
    const float* fc_w   = (const float*)d_in[1];
    const float* fc_b   = (const float*)d_in[2];
    const float* attn_w = (const float*)d_in[3];
    // attn_b (d_in[4]) cancels in the softmax — unused.
    float* wsf = (float*)d_ws;
    float* out = (float*)d_out;

    float* w2   = wsf;
    float* s2   = wsf + 1024;
    float* part = s2 + BATCH * NROWS;
    float* y    = part + (size_t)NBLK * IN_DIM;
    float* cb   = y + BATCH * IN_DIM;

    bool coop_ok = false;
    if (ws_size >= (size_t)(1024 + BATCH * NROWS + NBLK * IN_DIM +
                            BATCH * IN_DIM + BATCH * OUT_DIM) * sizeof(float)) {
        void* args[] = { (void*)&x, (void*)&fc_w, (void*)&fc_b, (void*)&attn_w,
                         (void*)&wsf, (void*)&out };
        hipError_t e = hipLaunchCooperativeKernel((const void*)coop_all,
                                                  dim3(NBLK), dim3(256), args, 0, stream);
        coop_ok = (e == hipSuccess);
    }
    if (!coop_ok) {
        fb_w2   <<<16,  256, 0, stream>>>(fc_w, attn_w, w2);
        fb_s2   <<<NBLK,256, 0, stream>>>(x, w2, s2);
        fb_part <<<NBLK,256, 0, stream>>>(x, s2, part);
        fb_yred <<<64,  256, 0, stream>>>(part, y);
        fb_c    <<<128, 256, 0, stream>>>(y, fc_w, fc_b, cb);
        fb_bcast<<<NBLK,256, 0, stream>>>(cb, out);
    }
}

// Round 5
// 39.813 us; speedup vs baseline: 4.3534x; 4.3534x over previous
//
#include <hip/hip_runtime.h>

#define BATCH 4
#define NROWS 2048
#define IN_DIM 1024
#define OUT_DIM 512
#define DSPLIT 8
#define NCHUNK 256          // chunks total (64 per batch)
#define RPB 32              // rows per chunk

// ---- K1: w2part[ds][col] = sum_{d in slice} fc_w[d][col] * a2[d] ------
__global__ void __launch_bounds__(256)
k1_w2part(const float* __restrict__ fc_w,
          const float* __restrict__ attn_w,
          float* __restrict__ w2part) {
    int ds = blockIdx.x >> 2, cg = blockIdx.x & 3;   // 32 blocks
    int col = (cg << 8) + threadIdx.x;
    int d0 = ds << 6;
    float acc = 0.f;
#pragma unroll 8
    for (int j = 0; j < 64; ++j)
        acc += fc_w[(size_t)(d0 + j) * IN_DIM + col] * attn_w[OUT_DIM + d0 + j];
    w2part[(ds << 10) + col] = acc;
}

// ---- K2: per-chunk flash pass: yu_c = sum_r e^{s2_r} x_r, Zc = sum e --
// 256 blocks x 512 threads; 8 waves, each wave owns 4 rows; x read ONCE.
__global__ void __launch_bounds__(512)
k2_chunk(const float* __restrict__ x,
         const float* __restrict__ w2part,
         float* __restrict__ yu,
         float* __restrict__ Zc) {
    const int bid = blockIdx.x, t = threadIdx.x;
    const int w = t >> 6, lane = t & 63;
    __shared__ float w2s[IN_DIM];                 // 4 KB
    __shared__ float4 sbuf[8 * 256];              // 32 KB
    __shared__ float zbuf[8];

    // merge the 8 w2 partial slices into LDS (first 256 threads)
    if (t < 256) {
        const float4* wp = (const float4*)w2part;
        float4 s = {0.f, 0.f, 0.f, 0.f};
#pragma unroll
        for (int ds = 0; ds < DSPLIT; ++ds) {
            float4 v = wp[(ds << 8) + t];
            s.x += v.x; s.y += v.y; s.z += v.z; s.w += v.w;
        }
        ((float4*)w2s)[t] = s;
    }
    __syncthreads();

    const float4* x4 = (const float4*)x;
    const float4* w2s4 = (const float4*)w2s;
    const float4 u0 = w2s4[lane],       u1 = w2s4[lane + 64],
                 u2 = w2s4[lane + 128], u3 = w2s4[lane + 192];

    size_t row0 = (size_t)bid * RPB + (w << 2);
    float4 a0 = {0,0,0,0}, a1 = {0,0,0,0}, a2 = {0,0,0,0}, a3 = {0,0,0,0};
    float zw = 0.f;
#pragma unroll
    for (int r = 0; r < 4; ++r) {
        size_t base = (row0 + r) << 8;            // f4 units
        float4 v0 = x4[base + lane];
        float4 v1 = x4[base + lane + 64];
        float4 v2 = x4[base + lane + 128];
        float4 v3 = x4[base + lane + 192];
        float d = v0.x*u0.x + v0.y*u0.y + v0.z*u0.z + v0.w*u0.w
                + v1.x*u1.x + v1.y*u1.y + v1.z*u1.z + v1.w*u1.w
                + v2.x*u2.x + v2.y*u2.y + v2.z*u2.z + v2.w*u2.w
                + v3.x*u3.x + v3.y*u3.y + v3.z*u3.z + v3.w*u3.w;
#pragma unroll
        for (int off = 32; off; off >>= 1) d += __shfl_xor(d, off, 64);
        float e = __expf(d);                       // |d| small: safe, exact softmax algebra
        zw += e;
        a0.x += e*v0.x; a0.y += e*v0.y; a0.z += e*v0.z; a0.w += e*v0.w;
        a1.x += e*v1.x; a1.y += e*v1.y; a1.z += e*v1.z; a1.w += e*v1.w;
        a2.x += e*v2.x; a2.y += e*v2.y; a2.z += e*v2.z; a2.w += e*v2.w;
        a3.x += e*v3.x; a3.y += e*v3.y; a3.z += e*v3.z; a3.w += e*v3.w;
    }
    sbuf[(w << 8) + lane]       = a0;
    sbuf[(w << 8) + lane + 64]  = a1;
    sbuf[(w << 8) + lane + 128] = a2;
    sbuf[(w << 8) + lane + 192] = a3;
    if (lane == 0) zbuf[w] = zw;
    __syncthreads();

    if (t < 256) {
        float4 s = {0.f, 0.f, 0.f, 0.f};
#pragma unroll
        for (int i = 0; i < 8; ++i) {
            float4 v = sbuf[(i << 8) + t];
            s.x += v.x; s.y += v.y; s.z += v.z; s.w += v.w;
        }
        ((float4*)(yu + ((size_t)bid << 10)))[t] = s;
        if (t == 0) {
            float z = 0.f;
#pragma unroll
            for (int i = 0; i < 8; ++i) z += zbuf[i];
            Zc[bid] = z;
        }
    }
}

// ---- K3: y[b] = (sum_c yu_c)/Z ; c[b][d] = y.fc_w[d] + fc_b[d] --------
// 32 blocks: b(4) x dslice(8, 64 d each); waves do 16 d's each.
__global__ void __launch_bounds__(256)
k3_yc(const float* __restrict__ yu,
      const float* __restrict__ Zc,
      const float* __restrict__ fc_w,
      const float* __restrict__ fc_b,
      float* __restrict__ cb) {
    const int b = blockIdx.x >> 3, ds = blockIdx.x & 7;
    const int t = threadIdx.x, w = t >> 6, lane = t & 63;
    __shared__ float ys[IN_DIM];

    float z = Zc[(b << 6) + lane];     // 64 chunk sums of this batch
#pragma unroll
    for (int off = 32; off; off >>= 1) z += __shfl_xor(z, off, 64);
    const float invZ = 1.f / z;

    const float4* yu4 = (const float4*)yu + ((size_t)b << 14);
    float4 acc = {0.f, 0.f, 0.f, 0.f};
#pragma unroll 4
    for (int c = 0; c < 64; ++c) {
        float4 v = yu4[(c << 8) + t];
        acc.x += v.x; acc.y += v.y; acc.z += v.z; acc.w += v.w;
    }
    acc.x *= invZ; acc.y *= invZ; acc.z *= invZ; acc.w *= invZ;
    ((float4*)ys)[t] = acc;
    __syncthreads();

    const float4* ys4 = (const float4*)ys;
    const float4 y0 = ys4[lane],       y1 = ys4[lane + 64],
                 y2 = ys4[lane + 128], y3 = ys4[lane + 192];
#pragma unroll 2
    for (int q = 0; q < 16; ++q) {
        int d = (ds << 6) + (w << 4) + q;
        const float4* fr = (const float4*)fc_w + ((size_t)d << 8);
        float4 f0 = fr[lane], f1 = fr[lane + 64], f2 = fr[lane + 128], f3 = fr[lane + 192];
        float s = f0.x*y0.x + f0.y*y0.y + f0.z*y0.z + f0.w*y0.w
                + f1.x*y1.x + f1.y*y1.y + f1.z*y1.z + f1.w*y1.w
                + f2.x*y2.x + f2.y*y2.y + f2.z*y2.z + f2.w*y2.w
                + f3.x*y3.x + f3.y*y3.y + f3.z*y3.z + f3.w*y3.w;
#pragma unroll
        for (int off = 32; off; off >>= 1) s += __shfl_xor(s, off, 64);
        if (lane == 0) cb[(b << 9) + d] = s + fc_b[d];
    }
}

// ---- K4: out[b,n,:] = c[b,:] broadcast (8 rows per block) --------------
__global__ void __launch_bounds__(256)
k4_bcast(const float* __restrict__ cb, float4* __restrict__ out) {
    const int bid = blockIdx.x, t = threadIdx.x;
    const int b = bid >> 8;
    __shared__ float4 cs[128];
    if (t < 128) cs[t] = ((const float4*)cb)[(b << 7) + t];
    __syncthreads();
    float4* o = out + ((size_t)bid << 10);
#pragma unroll
    for (int j = 0; j < 4; ++j) {
        int idx = (j << 8) + t;
        o[idx] = cs[idx & 127];
    }
}

extern "C" void kernel_launch(void* const* d_in, const int* in_sizes, int n_in,
                              void* d_out, int out_size, void* d_ws, size_t ws_size,
                              hipStream_t stream) {
    const float* x      = (const float*)d_in[0];
    const float* fc_w   = (const float*)d_in[1];
    const float* fc_b   = (const float*)d_in[2];
    const float* attn_w = (const float*)d_in[3];
    // attn_b (d_in[4]) cancels in the softmax — unused.

    float* wsf    = (float*)d_ws;
    float* w2part = wsf;                               // 8192
    float* Zc     = w2part + DSPLIT * IN_DIM;          // 256
    float* yu     = Zc + NCHUNK;                       // 262144
    float* cb     = yu + (size_t)NCHUNK * IN_DIM;      // 2048
    float* out    = (float*)d_out;                     // total ws: 1.09 MB

    k1_w2part<<<32,   256, 0, stream>>>(fc_w, attn_w, w2part);
    k2_chunk <<<NCHUNK, 512, 0, stream>>>(x, w2part, yu, Zc);
    k3_yc    <<<32,   256, 0, stream>>>(yu, Zc, fc_w, fc_b, cb);
    k4_bcast <<<1024, 256, 0, stream>>>(cb, (float4*)out);
}